// Round 7
// baseline (54.356 us; speedup 1.0000x reference)
//
#include <hip/hip_runtime.h>

namespace {
constexpr int   kCells     = 512 * 28 * 28;        // 401408
constexpr int   kTPB       = 256;                  // 4 waves
constexpr int   kTileCells = 256;                  // one cell per thread per tile
constexpr int   kTileF     = kTileCells * 30;      // 7680 floats per tensor
constexpr int   kTileC4    = kTileF / 4;           // 1920 float4 per tensor
constexpr int   kNTiles    = kCells / kTileCells;  // 1568 (exact)
constexpr int   kNBlk      = 512;                  // 2 blocks/CU (LDS-limited)
constexpr int   kBaseT     = kNTiles / kNBlk;      // 3
constexpr int   kExtraT    = kNTiles % kNBlk;      // 32 blocks take 4 tiles
constexpr float kLCoord    = 5.0f;
constexpr float kLNoobj    = 0.5f;
constexpr float kInvS      = 1.0f / 28.0f;
constexpr float kInvN      = 1.0f / 512.0f;
}

// p, t point at one cell's 30 floats (in LDS).
__device__ __forceinline__ float cell_loss(const float* p, const float* t) {
    const float coo = (t[4] > 0.0f) ? 1.0f : 0.0f;

    const float t_cx = t[0] * kInvS, t_cy = t[1] * kInvS;
    const float t_ltx = t_cx - 0.5f * t[2];
    const float t_lty = t_cy - 0.5f * t[3];
    const float t_rbx = t_cx + 0.5f * t[2];
    const float t_rby = t_cy + 0.5f * t[3];
    const float area2 = (t_rbx - t_ltx) * (t_rby - t_lty);

    float iou0 = 0.0f, iou1 = 0.0f;
    #pragma unroll
    for (int b = 0; b < 2; ++b) {
        const float* pb = p + 5 * b;
        const float p_cx = pb[0] * kInvS, p_cy = pb[1] * kInvS;
        const float p_ltx = p_cx - 0.5f * pb[2];
        const float p_lty = p_cy - 0.5f * pb[3];
        const float p_rbx = p_cx + 0.5f * pb[2];
        const float p_rby = p_cy + 0.5f * pb[3];
        const float ltx = fmaxf(p_ltx, t_ltx);
        const float lty = fmaxf(p_lty, t_lty);
        const float rbx = fminf(p_rbx, t_rbx);
        const float rby = fminf(p_rby, t_rby);
        const float w = fmaxf(rbx - ltx, 0.0f);
        const float h = fmaxf(rby - lty, 0.0f);
        const float inter = w * h;
        const float area1 = (p_rbx - p_ltx) * (p_rby - p_lty);
        const float iou = inter / (area1 + area2 - inter);
        if (b == 0) iou0 = iou; else iou1 = iou;
    }
    // jnp.argmax picks the FIRST max on ties -> idx 1 only if strictly greater.
    const int   max_idx = (iou1 > iou0) ? 1 : 0;
    const float max_iou = fmaxf(iou0, iou1);

    float loc = 0.0f, contain = 0.0f, notresp = 0.0f, nooobj = 0.0f;
    #pragma unroll
    for (int b = 0; b < 2; ++b) {
        const float* pb = p + 5 * b;
        const float* tb = t + 5 * b;
        const float dx = pb[0] - tb[0];
        const float dy = pb[1] - tb[1];
        const float d_xy = dx * dx + dy * dy;
        const float sw = sqrtf(pb[2]) - sqrtf(tb[2]);
        const float sh = sqrtf(pb[3]) - sqrtf(tb[3]);
        const float d_wh = sw * sw + sh * sh;
        const float resp   = (b == max_idx) ? 1.0f : 0.0f;
        const float w_resp = coo * resp;
        const float w_not  = coo * (1.0f - resp);
        loc += w_resp * (d_xy + d_wh);
        const float dc = pb[4] - max_iou;
        contain += w_resp * dc * dc;
        notresp += w_not * pb[4] * pb[4];
        const float dn = pb[4] - tb[4];
        nooobj += (1.0f - coo) * dn * dn;
    }

    float cls = 0.0f;
    #pragma unroll
    for (int j = 10; j < 30; ++j) {
        const float d = p[j] - t[j];
        cls += d * d;
    }
    cls *= coo;

    return kLCoord * loc + contain + kLNoobj * (notresp + nooobj) + cls;
}

// Persistent 4-wave blocks over contiguous tile ranges. Staging via PLAIN
// coalesced float4 loads -> registers -> ds_write_b128 (no global_load_lds).
// T14 split: issue tile i+1's loads right after writing tile i to LDS, so
// HBM latency hides under tile i's compute. Single LDS buffer (regs are the
// second buffer).
template <bool USE_WS>
__global__ __launch_bounds__(kTPB, 2) void yolo_loss_kernel(
        const float* __restrict__ pred,
        const float* __restrict__ targ,
        float* __restrict__ dst) {
    __shared__ float4 lds4[2 * kTileC4];   // [0,1920): pred, [1920,3840): targ
    __shared__ float wsum[kTPB / 64];

    const int tid  = threadIdx.x;
    const int lane = tid & 63;
    const int wid  = tid >> 6;
    const int b    = blockIdx.x;

    const int t0 = b * kBaseT + min(b, kExtraT);
    const int H  = kBaseT + (b < kExtraT ? 1 : 0);

    float* lds = reinterpret_cast<float*>(lds4);

    float4 r[15];
    // 15 float4/thread: chunks g = c*256+tid over [pred_tile | targ_tile].
    // The pred/targ split lands on a wave boundary at c==7 -> uniform select.
    auto issue = [&](int tile) {
        const float* gp = pred + (size_t)tile * kTileF;
        const float* gt = targ + (size_t)tile * kTileF;
        #pragma unroll
        for (int c = 0; c < 15; ++c) {
            const int g = c * kTPB + tid;
            const float* src = (g < kTileC4) ? (gp + (size_t)g * 4)
                                             : (gt + (size_t)(g - kTileC4) * 4);
            r[c] = *reinterpret_cast<const float4*>(src);
        }
    };
    auto store = [&]() {
        #pragma unroll
        for (int c = 0; c < 15; ++c)
            lds4[c * kTPB + tid] = r[c];
    };

    issue(t0);
    float acc = 0.0f;
    for (int i = 0; i < H; ++i) {
        if (i) {
            // all waves' ds ops done + all waves past reads of tile i-1
            asm volatile("s_waitcnt lgkmcnt(0)" ::: "memory");
            __builtin_amdgcn_s_barrier();
        }
        store();                              // vmcnt waits inserted by compiler
        if (i + 1 < H) issue(t0 + i + 1);     // prefetch; lands during compute
        asm volatile("s_waitcnt lgkmcnt(0)" ::: "memory");
        __builtin_amdgcn_s_barrier();         // tile i fully visible in LDS
        acc += cell_loss(lds + tid * 30, lds + kTileF + tid * 30);
    }

    #pragma unroll
    for (int off = 32; off > 0; off >>= 1)
        acc += __shfl_down(acc, off, 64);
    if (lane == 0) wsum[wid] = acc;
    __syncthreads();
    if (tid == 0) {
        const float s = wsum[0] + wsum[1] + wsum[2] + wsum[3];
        if (USE_WS) dst[b] = s;
        else        atomicAdd(dst, s * kInvN);
    }
}

__global__ __launch_bounds__(256) void reduce_kernel(
        const float* __restrict__ part, float* __restrict__ out) {
    __shared__ float wsum[4];
    float s = 0.0f;
    for (int i = threadIdx.x; i < kNBlk; i += 256) s += part[i];
    #pragma unroll
    for (int off = 32; off > 0; off >>= 1)
        s += __shfl_down(s, off, 64);
    const int lane = threadIdx.x & 63;
    const int wid  = threadIdx.x >> 6;
    if (lane == 0) wsum[wid] = s;
    __syncthreads();
    if (threadIdx.x == 0)
        out[0] = (wsum[0] + wsum[1] + wsum[2] + wsum[3]) * kInvN;
}

__global__ void zero_out_kernel(float* __restrict__ out) {
    if (threadIdx.x == 0) out[0] = 0.0f;
}

extern "C" void kernel_launch(void* const* d_in, const int* in_sizes, int n_in,
                              void* d_out, int out_size, void* d_ws, size_t ws_size,
                              hipStream_t stream) {
    const float* pred = (const float*)d_in[0];
    const float* targ = (const float*)d_in[1];
    float* out = (float*)d_out;

    if (ws_size >= (size_t)kNBlk * sizeof(float)) {
        float* part = (float*)d_ws;
        yolo_loss_kernel<true><<<kNBlk, kTPB, 0, stream>>>(pred, targ, part);
        reduce_kernel<<<1, 256, 0, stream>>>(part, out);
    } else {
        zero_out_kernel<<<1, 64, 0, stream>>>(out);
        yolo_loss_kernel<false><<<kNBlk, kTPB, 0, stream>>>(pred, targ, out);
    }
}

// Round 8
// 23.268 us; speedup vs baseline: 2.3360x; 2.3360x over previous
//
#include <hip/hip_runtime.h>

namespace {
constexpr int   kCells     = 512 * 28 * 28;        // 401408
constexpr int   kTPB       = 256;                  // 4 waves
constexpr int   kTileCells = 256;                  // one cell per thread per tile
constexpr int   kTileF     = kTileCells * 30;      // 7680 floats per tensor
constexpr int   kTileC4    = kTileF / 4;           // 1920 float4 per tensor
constexpr int   kNTiles    = kCells / kTileCells;  // 1568 (exact)
constexpr int   kNBlk      = 512;                  // 2 blocks/CU (LDS-limited)
constexpr int   kBaseT     = kNTiles / kNBlk;      // 3
constexpr int   kExtraT    = kNTiles % kNBlk;      // 32 blocks take 4 tiles
constexpr float kLCoord    = 5.0f;
constexpr float kLNoobj    = 0.5f;
constexpr float kInvS      = 1.0f / 28.0f;
constexpr float kInvN      = 1.0f / 512.0f;
}

// p, t point at one cell's 30 floats (in LDS).
__device__ __forceinline__ float cell_loss(const float* p, const float* t) {
    const float coo = (t[4] > 0.0f) ? 1.0f : 0.0f;

    const float t_cx = t[0] * kInvS, t_cy = t[1] * kInvS;
    const float t_ltx = t_cx - 0.5f * t[2];
    const float t_lty = t_cy - 0.5f * t[3];
    const float t_rbx = t_cx + 0.5f * t[2];
    const float t_rby = t_cy + 0.5f * t[3];
    const float area2 = (t_rbx - t_ltx) * (t_rby - t_lty);

    float iou0 = 0.0f, iou1 = 0.0f;
    #pragma unroll
    for (int b = 0; b < 2; ++b) {
        const float* pb = p + 5 * b;
        const float p_cx = pb[0] * kInvS, p_cy = pb[1] * kInvS;
        const float p_ltx = p_cx - 0.5f * pb[2];
        const float p_lty = p_cy - 0.5f * pb[3];
        const float p_rbx = p_cx + 0.5f * pb[2];
        const float p_rby = p_cy + 0.5f * pb[3];
        const float ltx = fmaxf(p_ltx, t_ltx);
        const float lty = fmaxf(p_lty, t_lty);
        const float rbx = fminf(p_rbx, t_rbx);
        const float rby = fminf(p_rby, t_rby);
        const float w = fmaxf(rbx - ltx, 0.0f);
        const float h = fmaxf(rby - lty, 0.0f);
        const float inter = w * h;
        const float area1 = (p_rbx - p_ltx) * (p_rby - p_lty);
        const float iou = inter / (area1 + area2 - inter);
        if (b == 0) iou0 = iou; else iou1 = iou;
    }
    // jnp.argmax picks the FIRST max on ties -> idx 1 only if strictly greater.
    const int   max_idx = (iou1 > iou0) ? 1 : 0;
    const float max_iou = fmaxf(iou0, iou1);

    float loc = 0.0f, contain = 0.0f, notresp = 0.0f, nooobj = 0.0f;
    #pragma unroll
    for (int b = 0; b < 2; ++b) {
        const float* pb = p + 5 * b;
        const float* tb = t + 5 * b;
        const float dx = pb[0] - tb[0];
        const float dy = pb[1] - tb[1];
        const float d_xy = dx * dx + dy * dy;
        const float sw = sqrtf(pb[2]) - sqrtf(tb[2]);
        const float sh = sqrtf(pb[3]) - sqrtf(tb[3]);
        const float d_wh = sw * sw + sh * sh;
        const float resp   = (b == max_idx) ? 1.0f : 0.0f;
        const float w_resp = coo * resp;
        const float w_not  = coo * (1.0f - resp);
        loc += w_resp * (d_xy + d_wh);
        const float dc = pb[4] - max_iou;
        contain += w_resp * dc * dc;
        notresp += w_not * pb[4] * pb[4];
        const float dn = pb[4] - tb[4];
        nooobj += (1.0f - coo) * dn * dn;
    }

    float cls = 0.0f;
    #pragma unroll
    for (int j = 10; j < 30; ++j) {
        const float d = p[j] - t[j];
        cls += d * d;
    }
    cls *= coo;

    return kLCoord * loc + contain + kLNoobj * (notresp + nooobj) + cls;
}

// Persistent 4-wave blocks over contiguous tile ranges. Staging via plain
// coalesced float4 loads into FIFTEEN NAMED registers (no array -> no scratch),
// then ds_write. T14 split: next tile's loads issue before this tile's compute.
// chunk index g = c*256+tid over [pred_tile(1920 float4) | targ_tile(1920)];
// the split at g==1920 is c==7, tid==128 -> wave-uniform halves within c==7.
template <bool USE_WS>
__global__ __launch_bounds__(kTPB) void yolo_loss_kernel(
        const float* __restrict__ pred,
        const float* __restrict__ targ,
        float* __restrict__ dst) {
    __shared__ float4 lds4[2 * kTileC4];   // 61440 B: [0,1920) pred, [1920,3840) targ
    __shared__ float wsum[kTPB / 64];

    const int tid  = threadIdx.x;
    const int lane = tid & 63;
    const int wid  = tid >> 6;
    const int b    = blockIdx.x;

    const int t0 = b * kBaseT + min(b, kExtraT);
    const int H  = kBaseT + (b < kExtraT ? 1 : 0);

    float* lds = reinterpret_cast<float*>(lds4);
    const float4* predv = reinterpret_cast<const float4*>(pred);
    const float4* targv = reinterpret_cast<const float4*>(targ);

    float4 r0, r1, r2, r3, r4, r5, r6, r7, r8, r9, r10, r11, r12, r13, r14;

#define YL_ADDR(c) (((c) * kTPB + tid) < kTileC4                                  \
        ? gp + ((c) * kTPB + tid)                                                 \
        : gt + ((c) * kTPB + tid - kTileC4))
#define YL_ISSUE(tile) do {                                                       \
        const float4* gp = predv + (size_t)(tile) * kTileC4;                      \
        const float4* gt = targv + (size_t)(tile) * kTileC4;                      \
        r0  = *YL_ADDR(0);  r1  = *YL_ADDR(1);  r2  = *YL_ADDR(2);                \
        r3  = *YL_ADDR(3);  r4  = *YL_ADDR(4);  r5  = *YL_ADDR(5);                \
        r6  = *YL_ADDR(6);  r7  = *YL_ADDR(7);  r8  = *YL_ADDR(8);                \
        r9  = *YL_ADDR(9);  r10 = *YL_ADDR(10); r11 = *YL_ADDR(11);               \
        r12 = *YL_ADDR(12); r13 = *YL_ADDR(13); r14 = *YL_ADDR(14);               \
    } while (0)
#define YL_STORE() do {                                                           \
        lds4[ 0 * kTPB + tid] = r0;  lds4[ 1 * kTPB + tid] = r1;                  \
        lds4[ 2 * kTPB + tid] = r2;  lds4[ 3 * kTPB + tid] = r3;                  \
        lds4[ 4 * kTPB + tid] = r4;  lds4[ 5 * kTPB + tid] = r5;                  \
        lds4[ 6 * kTPB + tid] = r6;  lds4[ 7 * kTPB + tid] = r7;                  \
        lds4[ 8 * kTPB + tid] = r8;  lds4[ 9 * kTPB + tid] = r9;                  \
        lds4[10 * kTPB + tid] = r10; lds4[11 * kTPB + tid] = r11;                 \
        lds4[12 * kTPB + tid] = r12; lds4[13 * kTPB + tid] = r13;                 \
        lds4[14 * kTPB + tid] = r14;                                              \
    } while (0)

    YL_ISSUE(t0);
    float acc = 0.0f;
    for (int i = 0; i < H; ++i) {
        if (i) __builtin_amdgcn_s_barrier();   // all waves done reading tile i-1
        YL_STORE();                            // compiler waits vmcnt per reg use
        if (i + 1 < H) YL_ISSUE(t0 + i + 1);   // prefetch: lands during compute
        asm volatile("s_waitcnt lgkmcnt(0)" ::: "memory");
        __builtin_amdgcn_s_barrier();          // tile i fully visible in LDS
        acc += cell_loss(lds + tid * 30, lds + kTileF + tid * 30);
    }
#undef YL_ADDR
#undef YL_ISSUE
#undef YL_STORE

    #pragma unroll
    for (int off = 32; off > 0; off >>= 1)
        acc += __shfl_down(acc, off, 64);
    if (lane == 0) wsum[wid] = acc;
    __syncthreads();
    if (tid == 0) {
        const float s = wsum[0] + wsum[1] + wsum[2] + wsum[3];
        if (USE_WS) dst[b] = s;
        else        atomicAdd(dst, s * kInvN);
    }
}

__global__ __launch_bounds__(256) void reduce_kernel(
        const float* __restrict__ part, float* __restrict__ out) {
    __shared__ float wsum[4];
    float s = 0.0f;
    for (int i = threadIdx.x; i < kNBlk; i += 256) s += part[i];
    #pragma unroll
    for (int off = 32; off > 0; off >>= 1)
        s += __shfl_down(s, off, 64);
    const int lane = threadIdx.x & 63;
    const int wid  = threadIdx.x >> 6;
    if (lane == 0) wsum[wid] = s;
    __syncthreads();
    if (threadIdx.x == 0)
        out[0] = (wsum[0] + wsum[1] + wsum[2] + wsum[3]) * kInvN;
}

__global__ void zero_out_kernel(float* __restrict__ out) {
    if (threadIdx.x == 0) out[0] = 0.0f;
}

extern "C" void kernel_launch(void* const* d_in, const int* in_sizes, int n_in,
                              void* d_out, int out_size, void* d_ws, size_t ws_size,
                              hipStream_t stream) {
    const float* pred = (const float*)d_in[0];
    const float* targ = (const float*)d_in[1];
    float* out = (float*)d_out;

    if (ws_size >= (size_t)kNBlk * sizeof(float)) {
        float* part = (float*)d_ws;
        yolo_loss_kernel<true><<<kNBlk, kTPB, 0, stream>>>(pred, targ, part);
        reduce_kernel<<<1, 256, 0, stream>>>(part, out);
    } else {
        zero_out_kernel<<<1, 64, 0, stream>>>(out);
        yolo_loss_kernel<false><<<kNBlk, kTPB, 0, stream>>>(pred, targ, out);
    }
}